// Round 6
// baseline (279.131 us; speedup 1.0000x reference)
//
#include <hip/hip_runtime.h>

typedef unsigned short u16;
typedef __bf16 bf16x8 __attribute__((ext_vector_type(8)));
typedef float f32x4 __attribute__((ext_vector_type(4)));
typedef u16 u16x8 __attribute__((ext_vector_type(8)));
typedef u16 u16x4 __attribute__((ext_vector_type(4)));

typedef __attribute__((address_space(1))) const unsigned char gc_u8;
typedef __attribute__((address_space(3))) unsigned char lds_u8;

__device__ inline void gload16(const void* g, void* l) {
    __builtin_amdgcn_global_load_lds((gc_u8*)g, (lds_u8*)l, 16, 0, 0);
}
__device__ inline u16 f2bf(float f) {
    union { __bf16 h; u16 u; } c; c.h = (__bf16)f; return c.u;
}
// Fully-fenced barrier: nothing (incl. register-only MFMA / ds_read) crosses.
__device__ inline void hard_barrier() {
    __builtin_amdgcn_sched_barrier(0);
    __builtin_amdgcn_s_barrier();
    __builtin_amdgcn_sched_barrier(0);
}
#define WAIT_LGKM0() asm volatile("s_waitcnt lgkmcnt(0)" ::: "memory")
#define WAIT_VMCNT(n) asm volatile("s_waitcnt vmcnt(" #n ")" ::: "memory")

// ---------------- fp32 -> bf16 convert ----------------
__global__ __launch_bounds__(256) void cvt_bf16(const float* __restrict__ src,
                                                u16* __restrict__ dst, int n) {
    int i = (blockIdx.x * 256 + threadIdx.x) * 4;
    if (i < n) {
        float4 f = *reinterpret_cast<const float4*>(src + i);
        u16x4 u = { f2bf(f.x), f2bf(f.y), f2bf(f.z), f2bf(f.w) };
        *reinterpret_cast<u16x4*>(dst + i) = u;
    }
}

// ---------------- NT GEMM: C[M,N] = A[M,K] * B[N,K]^T + bias ----------------
// A,B bf16 via global_load_lds, 2-phase dbuf with hardened fences.
// OUT_MODE: 0 = bf16 [M][N]; 1 = f32 [M][N]; 2 = bf16 V^T head layout (b,h,dk,s).
template <int OUT_MODE>
__global__ __launch_bounds__(256) void gemm_nt(const u16* __restrict__ A,
                                               const u16* __restrict__ B,
                                               const float* __restrict__ bias,
                                               void* __restrict__ Cv,
                                               int M, int N, int K) {
    __shared__ __align__(16) u16 As[2][128][32];
    __shared__ __align__(16) u16 Bs[2][128][32];
    const int t = threadIdx.x, lane = t & 63, w = t >> 6;
    const int wr = w >> 1, wc = w & 1;
    const int l15 = lane & 15, l16 = lane >> 4;
    const int nwg = gridDim.x, ntiles = N >> 7;
    const int wg = blockIdx.x, chunk = nwg >> 3;
    const int swz = (wg & 7) * chunk + (wg >> 3);
    const int bm = (swz / ntiles) * 128, bn = (swz % ntiles) * 128;
    const int srow = w * 16 + (lane >> 2);
    const int sgr = (lane & 3) * 8;
    const u16* Ab = A + (size_t)bm * K;
    const u16* Bb = B + (size_t)bn * K;

    f32x4 acc[4][4];
#pragma unroll
    for (int i = 0; i < 4; i++)
#pragma unroll
        for (int j = 0; j < 4; j++) acc[i][j] = (f32x4){0.f, 0.f, 0.f, 0.f};

    auto stage = [&](int c, int k0) {
        gload16(Ab + (size_t)srow * K + k0 + sgr,        &As[c][w * 16][0]);
        gload16(Ab + (size_t)(64 + srow) * K + k0 + sgr, &As[c][64 + w * 16][0]);
        gload16(Bb + (size_t)srow * K + k0 + sgr,        &Bs[c][w * 16][0]);
        gload16(Bb + (size_t)(64 + srow) * K + k0 + sgr, &Bs[c][64 + w * 16][0]);
    };

    stage(0, 0);
    __syncthreads();  // one-time full drain: buf0 staged

    const int NS = K >> 5;
    for (int ks = 0; ks < NS; ks += 2) {
#pragma unroll
        for (int hf = 0; hf < 2; hf++) {
            const int c = hf;
            const int kn = ks + hf + 1;  // next tile index
            WAIT_LGKM0();     // our LDS reads fully retired before anyone overwrites
            hard_barrier();   // barrier1: all waves done reading buf c^1
            if (kn < NS) {
                stage(c ^ 1, kn * 32);
                WAIT_VMCNT(4);            // cur landed, next in flight
            } else {
                WAIT_VMCNT(0);
            }
            hard_barrier();   // barrier2: buf c visible to all waves

            bf16x8 afr[4], bfr[4];
#pragma unroll
            for (int mi = 0; mi < 4; mi++)
                afr[mi] = *(const bf16x8*)&As[c][wr * 64 + mi * 16 + l15][l16 * 8];
#pragma unroll
            for (int ni = 0; ni < 4; ni++)
                bfr[ni] = *(const bf16x8*)&Bs[c][wc * 64 + ni * 16 + l15][l16 * 8];
#pragma unroll
            for (int mi = 0; mi < 4; mi++)
#pragma unroll
                for (int ni = 0; ni < 4; ni++)
                    acc[mi][ni] = __builtin_amdgcn_mfma_f32_16x16x32_bf16(
                        afr[mi], bfr[ni], acc[mi][ni], 0, 0, 0);
        }
    }

    // epilogue: C/D layout col = lane&15, row = (lane>>4)*4 + r
#pragma unroll
    for (int ni = 0; ni < 4; ni++) {
        const int col = bn + wc * 64 + ni * 16 + l15;
        const float bv = bias[col];
#pragma unroll
        for (int mi = 0; mi < 4; mi++) {
            const int r0 = bm + wr * 64 + mi * 16 + l16 * 4;
            if constexpr (OUT_MODE == 2) {  // V^T head layout, 4 tokens packed
                const int bb = r0 >> 11, ss = r0 & 2047;
                const int hh = col >> 6, dk = col & 63;
                u16x4 pk;
#pragma unroll
                for (int r = 0; r < 4; r++) pk[r] = f2bf(acc[mi][ni][r] + bv);
                *(u16x4*)&((u16*)Cv)[(((size_t)(bb * 16 + hh) * 64 + dk) << 11) + ss] = pk;
            } else {
#pragma unroll
                for (int r = 0; r < 4; r++) {
                    float v = acc[mi][ni][r] + bv;
                    if constexpr (OUT_MODE == 1)
                        ((float*)Cv)[(size_t)(r0 + r) * N + col] = v;
                    else
                        ((u16*)Cv)[(size_t)(r0 + r) * N + col] = f2bf(v);
                }
            }
        }
    }
}

// ---------------- flash attention (no-max softmax, dbuf KV, swizzled LDS) ----------------
// 64 q-rows per block (4 waves x 16). KV tiles of 64, double-buffered, fenced.
// K/V LDS XOR-granule swizzle: source granule g^((row>>1)&3), read same XOR.
__global__ __launch_bounds__(256) void attn_fwd(const u16* __restrict__ Q,
                                                const u16* __restrict__ Kg,
                                                const u16* __restrict__ Vt,
                                                const int* __restrict__ mask,
                                                u16* __restrict__ O) {
    constexpr int S = 2048, D = 1024;
    __shared__ __align__(16) u16 Kl[2][2][64][32];  // [buf][dk-half][key][dk32]
    __shared__ __align__(16) u16 Vl[2][2][64][32];  // [buf][k-half][dk][k32]
    __shared__ __align__(16) u16 Pl[4][16][68];     // per-wave P, padded stride
    __shared__ unsigned Mb[64];                     // 2048-key mask bitmap
    const int t = threadIdx.x, lane = t & 63, w = t >> 6;
    const int l15 = lane & 15, l16 = lane >> 4;
    const int wg = blockIdx.x;
    const int swz = (wg & 7) * 256 + (wg >> 3);
    const int q0 = (swz & 31) * 64, h = (swz >> 5) & 15, b = swz >> 9;
    const int srow = w * 16 + (lane >> 2);
    const int sgr = ((lane & 3) ^ ((lane >> 3) & 3)) * 8;   // pre-swizzled source granule
    const int gsw8 = (l16 ^ ((l15 >> 1) & 3)) * 8;          // swizzled read granule

    const u16* Khead = Kg + (size_t)b * S * D + h * 64;
    const u16* Vthead = Vt + (size_t)(b * 16 + h) * 64 * 2048;
    const int* mrow = mask + b * S;

    auto stage = [&](int c, int kt) {
        gload16(Khead + (size_t)(kt + srow) * D + sgr,        &Kl[c][0][w * 16][0]);
        gload16(Khead + (size_t)(kt + srow) * D + 32 + sgr,   &Kl[c][1][w * 16][0]);
        gload16(Vthead + (size_t)srow * 2048 + kt + sgr,      &Vl[c][0][w * 16][0]);
        gload16(Vthead + (size_t)srow * 2048 + kt + 32 + sgr, &Vl[c][1][w * 16][0]);
    };

    stage(0, 0);
    // pack mask bits (once)
#pragma unroll
    for (int j = 0; j < 8; j++) {
        unsigned long long bal = __ballot(mrow[j * 256 + w * 64 + lane] != 0);
        if (lane == 0) {
            Mb[(j * 4 + w) * 2]     = (unsigned)bal;
            Mb[(j * 4 + w) * 2 + 1] = (unsigned)(bal >> 32);
        }
    }

    // Q fragments, pre-scaled by 1/8
    bf16x8 aq[2];
#pragma unroll
    for (int ks = 0; ks < 2; ks++) {
        const size_t qi = ((size_t)b * S + q0 + w * 16 + l15) * D +
                          h * 64 + ks * 32 + l16 * 8;
        u16x8 raw = *(const u16x8*)&Q[qi];
        bf16x8 qv;
#pragma unroll
        for (int i = 0; i < 8; i++) {
            union { u16 u[2]; float f; } cu; cu.u[0] = 0; cu.u[1] = raw[i];
            qv[i] = (__bf16)(cu.f * 0.125f);
        }
        aq[ks] = qv;
    }

    f32x4 acc[4];
#pragma unroll
    for (int dt = 0; dt < 4; dt++) acc[dt] = (f32x4){0.f, 0.f, 0.f, 0.f};
    float lsum[4] = {};

    __syncthreads();  // one-time full drain: buf0 staged + Mb visible

    for (int kt = 0; kt < S; kt += 128) {
#pragma unroll
        for (int hf = 0; hf < 2; hf++) {
            const int c = hf;
            const int cur = kt + hf * 64, nxt = cur + 64;
            WAIT_LGKM0();     // our LDS reads fully retired before anyone overwrites
            hard_barrier();   // barrier1
            if (nxt < S) {
                stage(c ^ 1, nxt);
                WAIT_VMCNT(4);
            } else {
                WAIT_VMCNT(0);
            }
            hard_barrier();   // barrier2

            // QK^T
            f32x4 s[4];
#pragma unroll
            for (int k4 = 0; k4 < 4; k4++) {
                bf16x8 kf0 = *(const bf16x8*)&Kl[c][0][k4 * 16 + l15][gsw8];
                bf16x8 kf1 = *(const bf16x8*)&Kl[c][1][k4 * 16 + l15][gsw8];
                f32x4 z = (f32x4){0.f, 0.f, 0.f, 0.f};
                z = __builtin_amdgcn_mfma_f32_16x16x32_bf16(aq[0], kf0, z, 0, 0, 0);
                z = __builtin_amdgcn_mfma_f32_16x16x32_bf16(aq[1], kf1, z, 0, 0, 0);
                s[k4] = z;
            }

            // p = exp(s + madd); madd from bitmap
#pragma unroll
            for (int k4 = 0; k4 < 4; k4++) {
                const int key = cur + k4 * 16 + l15;
                const float madd = ((Mb[key >> 5] >> (key & 31)) & 1u) ? 0.f : -1.0e9f;
#pragma unroll
                for (int r = 0; r < 4; r++) {
                    float p = __expf(s[k4][r] + madd);
                    lsum[r] += p;
                    Pl[w][l16 * 4 + r][k4 * 16 + l15] = f2bf(p);
                }
            }

            // PV
            bf16x8 pa0 = *(const bf16x8*)&Pl[w][l15][l16 * 8];
            bf16x8 pa1 = *(const bf16x8*)&Pl[w][l15][32 + l16 * 8];
#pragma unroll
            for (int dt = 0; dt < 4; dt++) {
                bf16x8 vf0 = *(const bf16x8*)&Vl[c][0][dt * 16 + l15][gsw8];
                bf16x8 vf1 = *(const bf16x8*)&Vl[c][1][dt * 16 + l15][gsw8];
                acc[dt] = __builtin_amdgcn_mfma_f32_16x16x32_bf16(pa0, vf0, acc[dt], 0, 0, 0);
                acc[dt] = __builtin_amdgcn_mfma_f32_16x16x32_bf16(pa1, vf1, acc[dt], 0, 0, 0);
            }
        }
    }

    // epilogue: reduce lsum across l15 lanes (same q = l16*4+r), divide, store
#pragma unroll
    for (int r = 0; r < 4; r++) {
        float v = lsum[r];
#pragma unroll
        for (int off = 8; off >= 1; off >>= 1) v += __shfl_xor(v, off);
        lsum[r] = 1.f / v;
    }
#pragma unroll
    for (int dt = 0; dt < 4; dt++)
#pragma unroll
        for (int r = 0; r < 4; r++) {
            const int tok = q0 + w * 16 + l16 * 4 + r;
            O[((size_t)b * S + tok) * D + h * 64 + dt * 16 + l15] =
                f2bf(acc[dt][r] * lsum[r]);
        }
}

extern "C" void kernel_launch(void* const* d_in, const int* in_sizes, int n_in,
                              void* d_out, int out_size, void* d_ws, size_t ws_size,
                              hipStream_t stream) {
    const float* query = (const float*)d_in[0];
    const float* key   = (const float*)d_in[1];
    const float* value = (const float*)d_in[2];
    const int*   mask  = (const int*)d_in[3];
    const float* Wq = (const float*)d_in[4];
    const float* bq = (const float*)d_in[5];
    const float* Wk = (const float*)d_in[6];
    const float* bk = (const float*)d_in[7];
    const float* Wv = (const float*)d_in[8];
    const float* bv = (const float*)d_in[9];
    const float* Wo = (const float*)d_in[10];
    const float* bo = (const float*)d_in[11];
    float* out = (float*)d_out;

    constexpr int S = 2048, D = 1024;
    constexpr size_t MSZ = (size_t)4 * S * D;   // 8388608
    constexpr size_t WSZ = (size_t)D * D;       // 1048576
    const size_t need = 4 * WSZ * 2 + 4 * MSZ * 2;  // 72 MB
    if (ws_size < need) return;

    char* p = (char*)d_ws;
    u16* Wqb = (u16*)p; p += WSZ * 2;
    u16* Wkb = (u16*)p; p += WSZ * 2;
    u16* Wvb = (u16*)p; p += WSZ * 2;
    u16* Wob = (u16*)p; p += WSZ * 2;
    u16* Act = (u16*)p; p += MSZ * 2;  // reused: cvt'd activation, then attn output
    u16* Qb  = (u16*)p; p += MSZ * 2;
    u16* Kb  = (u16*)p; p += MSZ * 2;
    u16* Vtb = (u16*)p; p += MSZ * 2;  // (b,h,dk,s)

    cvt_bf16<<<1024, 256, 0, stream>>>(Wq, Wqb, (int)WSZ);
    cvt_bf16<<<1024, 256, 0, stream>>>(Wk, Wkb, (int)WSZ);
    cvt_bf16<<<1024, 256, 0, stream>>>(Wv, Wvb, (int)WSZ);
    cvt_bf16<<<1024, 256, 0, stream>>>(Wo, Wob, (int)WSZ);

    cvt_bf16<<<8192, 256, 0, stream>>>(query, Act, (int)MSZ);
    gemm_nt<0><<<512, 256, 0, stream>>>(Act, Wqb, bq, Qb, 8192, 1024, 1024);
    cvt_bf16<<<8192, 256, 0, stream>>>(key, Act, (int)MSZ);
    gemm_nt<0><<<512, 256, 0, stream>>>(Act, Wkb, bk, Kb, 8192, 1024, 1024);
    cvt_bf16<<<8192, 256, 0, stream>>>(value, Act, (int)MSZ);
    gemm_nt<2><<<512, 256, 0, stream>>>(Act, Wvb, bv, Vtb, 8192, 1024, 1024);

    attn_fwd<<<2048, 256, 0, stream>>>(Qb, Kb, Vtb, mask, Act);

    gemm_nt<1><<<512, 256, 0, stream>>>(Act, Wob, bo, out, 8192, 1024, 1024);
}